// Round 3
// baseline (615.063 us; speedup 1.0000x reference)
//
#include <hip/hip_runtime.h>
#include <math.h>

#define NN 100000
#define FIN 128
#define HID 16

// ---------------------------------------------------------------------------
// Edge dtype detection: if edge_index is int64 (little-endian, values < 2^17),
// every odd 32-bit word is zero. For int32 random values in [0,1e5) the odds
// of 128 consecutive odd words being zero are ~0.
__global__ void k_detect(const unsigned int* __restrict__ ew, int* __restrict__ flag) {
    __shared__ int nz;
    if (threadIdx.x == 0) nz = 0;
    __syncthreads();
    if (ew[2 * threadIdx.x + 1] != 0u) nz = 1;
    __syncthreads();
    if (threadIdx.x == 0) *flag = (nz == 0) ? 1 : 0;   // 1 => int64
}

__global__ void k_init_deg(float* __restrict__ deg, int n) {
    int i = blockIdx.x * blockDim.x + threadIdx.x;
    if (i < n) deg[i] = 1.0f;   // self-loop
}

__global__ void k_count(const void* __restrict__ ei, const int* __restrict__ flag,
                        float* __restrict__ deg, int E) {
    int e = blockIdx.x * blockDim.x + threadIdx.x;
    if (e >= E) return;
    int d;
    if (*flag) d = (int)((const long long*)ei)[E + e];
    else       d = ((const int*)ei)[E + e];
    atomicAdd(&deg[d], 1.0f);
}

__global__ void k_rsqrt(float* __restrict__ deg, int n) {
    int i = blockIdx.x * blockDim.x + threadIdx.x;
    if (i < n) deg[i] = rsqrtf(deg[i]);   // deg >= 1 always
}

// h1 = x @ W1 ; g1 = h1 * dis[i] ; agg1_init = b1 + g1 * dis[i]  (self-loop term)
__global__ __launch_bounds__(256) void k_gemm1(
    const float* __restrict__ x, const float* __restrict__ W1,
    const float* __restrict__ b1, const float* __restrict__ dis,
    float* __restrict__ g1, float* __restrict__ agg1, int n) {
    __shared__ float sW[FIN][HID];   // 8 KB
    for (int t = threadIdx.x; t < FIN * HID; t += 256) sW[t / HID][t % HID] = W1[t];
    __syncthreads();
    int i = blockIdx.x * 256 + threadIdx.x;
    if (i >= n) return;
    const float4* xr = (const float4*)(x + (size_t)i * FIN);
    float acc[HID];
#pragma unroll
    for (int c = 0; c < HID; ++c) acc[c] = 0.f;
    for (int k4 = 0; k4 < FIN / 4; ++k4) {
        float4 v = xr[k4];
#pragma unroll
        for (int c = 0; c < HID; ++c)
            acc[c] += v.x * sW[4*k4][c] + v.y * sW[4*k4+1][c]
                    + v.z * sW[4*k4+2][c] + v.w * sW[4*k4+3][c];
    }
    float di = dis[i];
    float* g1o = g1 + (size_t)i * HID;
    float* a1o = agg1 + (size_t)i * HID;
#pragma unroll
    for (int q = 0; q < 4; ++q) {
        float4 gv, av;
        gv.x = acc[4*q+0] * di; gv.y = acc[4*q+1] * di;
        gv.z = acc[4*q+2] * di; gv.w = acc[4*q+3] * di;
        av.x = b1[4*q+0] + gv.x * di; av.y = b1[4*q+1] + gv.y * di;
        av.z = b1[4*q+2] + gv.z * di; av.w = b1[4*q+3] + gv.w * di;
        *(float4*)(g1o + 4*q) = gv;
        *(float4*)(a1o + 4*q) = av;
    }
}

// Layer-1 aggregation: thread = (edge, channel); agg1[d][c] += g1[s][c] * dis[d]
__global__ void k_agg1(const void* __restrict__ ei, const int* __restrict__ flag,
                       const float* __restrict__ dis, const float* __restrict__ g1,
                       float* __restrict__ agg1, int E) {
    long long tid = (long long)blockIdx.x * blockDim.x + threadIdx.x;
    int e = (int)(tid >> 4);
    int c = (int)(tid & 15);
    if (e >= E) return;
    int s, d;
    if (*flag) {
        const long long* p = (const long long*)ei;
        s = (int)p[e]; d = (int)p[E + e];
    } else {
        const int* p = (const int*)ei;
        s = p[e]; d = p[E + e];
    }
    float v = g1[(size_t)s * HID + c] * dis[d];
    atomicAdd(&agg1[(size_t)d * HID + c], v);
}

// h2 = relu(agg1) @ W2 ; g2 = h2 * dis ; agg2_init = b2 + g2 * dis
__global__ void k_layer2(const float* __restrict__ agg1, const float* __restrict__ W2,
                         const float* __restrict__ b2, const float* __restrict__ dis,
                         float* __restrict__ g2, float* __restrict__ agg2, int n) {
    int i = blockIdx.x * blockDim.x + threadIdx.x;
    if (i >= n) return;
    const float* a = agg1 + (size_t)i * HID;
    float h0 = 0.f, h1 = 0.f;
#pragma unroll
    for (int q = 0; q < 4; ++q) {
        float4 v = *(const float4*)(a + 4*q);
        float r0 = fmaxf(v.x, 0.f), r1 = fmaxf(v.y, 0.f);
        float r2 = fmaxf(v.z, 0.f), r3 = fmaxf(v.w, 0.f);
        h0 += r0 * W2[(4*q+0)*2+0] + r1 * W2[(4*q+1)*2+0]
            + r2 * W2[(4*q+2)*2+0] + r3 * W2[(4*q+3)*2+0];
        h1 += r0 * W2[(4*q+0)*2+1] + r1 * W2[(4*q+1)*2+1]
            + r2 * W2[(4*q+2)*2+1] + r3 * W2[(4*q+3)*2+1];
    }
    float di = dis[i];
    float2 g; g.x = h0 * di; g.y = h1 * di;
    *(float2*)(g2 + 2*(size_t)i) = g;
    float2 a2; a2.x = b2[0] + g.x * di; a2.y = b2[1] + g.y * di;
    *(float2*)(agg2 + 2*(size_t)i) = a2;
}

// Layer-2 aggregation: thread = (edge, channel in {0,1})
__global__ void k_agg2(const void* __restrict__ ei, const int* __restrict__ flag,
                       const float* __restrict__ dis, const float* __restrict__ g2,
                       float* __restrict__ agg2, int E) {
    long long tid = (long long)blockIdx.x * blockDim.x + threadIdx.x;
    int e = (int)(tid >> 1);
    int c = (int)(tid & 1);
    if (e >= E) return;
    int s, d;
    if (*flag) {
        const long long* p = (const long long*)ei;
        s = (int)p[e]; d = (int)p[E + e];
    } else {
        const int* p = (const int*)ei;
        s = p[e]; d = p[E + e];
    }
    float v = g2[2*(size_t)s + c] * dis[d];
    atomicAdd(&agg2[2*(size_t)d + c], v);
}

__global__ void k_logsm(const float* __restrict__ agg2, float* __restrict__ out, int n) {
    int i = blockIdx.x * blockDim.x + threadIdx.x;
    if (i >= n) return;
    float2 z = *(const float2*)(agg2 + 2*(size_t)i);
    float m = fmaxf(z.x, z.y);
    float l = m + logf(expf(z.x - m) + expf(z.y - m));
    out[2*i]     = z.x - l;
    out[2*i + 1] = z.y - l;
}

extern "C" void kernel_launch(void* const* d_in, const int* in_sizes, int n_in,
                              void* d_out, int out_size, void* d_ws, size_t ws_size,
                              hipStream_t stream) {
    const float* x  = (const float*)d_in[0];
    const void*  ei = d_in[1];
    const float* W1 = (const float*)d_in[2];
    const float* b1 = (const float*)d_in[3];
    const float* W2 = (const float*)d_in[4];
    const float* b2 = (const float*)d_in[5];
    float* out = (float*)d_out;

    const int N = in_sizes[0] / FIN;     // 100000
    const int E = in_sizes[1] / 2;       // 3200000

    // workspace carve-up (peak ~13.2 MB).
    //   phase A (layer 1): flag | deg | g1 | agg1
    //   phase B (layer 2): flag | deg | g2+agg2 (overlay g1) | agg1
    // g1 is dead after k_agg1; g2/agg2 overlay its space.
    char* w = (char*)d_ws;
    int*   flag = (int*)w;            w += 256;
    float* deg  = (float*)w;          w += ((size_t)NN * 4 + 255) / 256 * 256;
    float* g1   = (float*)w;          // N*HID*4 = 6.4 MB
    float* g2   = g1;                 // overlays g1 (dead by then): N*2*4
    float* agg2 = g1 + (size_t)NN * 2; // after g2, still within g1's 6.4 MB
    w += (size_t)NN * HID * 4;
    float* agg1 = (float*)w;          w += (size_t)NN * HID * 4;

    const int nbN = (N + 255) / 256;
    const int nbE = (E + 255) / 256;

    k_detect<<<1, 128, 0, stream>>>((const unsigned int*)ei, flag);
    k_init_deg<<<nbN, 256, 0, stream>>>(deg, N);
    k_count<<<nbE, 256, 0, stream>>>(ei, flag, deg, E);
    k_rsqrt<<<nbN, 256, 0, stream>>>(deg, N);
    k_gemm1<<<nbN, 256, 0, stream>>>(x, W1, b1, deg, g1, agg1, N);

    long long t1 = (long long)E * HID;
    k_agg1<<<(int)((t1 + 255) / 256), 256, 0, stream>>>(ei, flag, deg, g1, agg1, E);

    k_layer2<<<nbN, 256, 0, stream>>>(agg1, W2, b2, deg, g2, agg2, N);

    long long t2 = (long long)E * 2;
    k_agg2<<<(int)((t2 + 255) / 256), 256, 0, stream>>>(ei, flag, deg, g2, agg2, E);

    k_logsm<<<nbN, 256, 0, stream>>>(agg2, out, N);
}